// Round 1
// baseline (309.881 us; speedup 1.0000x reference)
//
#include <hip/hip_runtime.h>
#include <hip/hip_bf16.h>
#include <stdint.h>

constexpr int kN = 16384;
constexpr int kD = 256;
constexpr int BM = 128, BN = 128, BK = 64;
constexpr int LDK = BK + 8;   // padded LDS row stride in bf16 elems (144 B) -> conflict-free b128 phases

using short8  = __attribute__((ext_vector_type(8))) short;   // 8 bf16 (4 VGPRs), MFMA A/B operand
using floatx4 = __attribute__((ext_vector_type(4))) float;   // MFMA C/D operand

__device__ __forceinline__ unsigned short f2bf_rne(float f) {
    uint32_t u = __float_as_uint(f);
    u += 0x7FFFu + ((u >> 16) & 1u);   // round-to-nearest-even
    return (unsigned short)(u >> 16);
}

// fp32 -> bf16 for both feature matrices (each N*D elems), 4 elems/thread
__global__ __launch_bounds__(256)
void cvt_bf16_kernel(const float* __restrict__ a, const float* __restrict__ b,
                     unsigned short* __restrict__ oa, unsigned short* __restrict__ ob) {
    int idx = (blockIdx.x * 256 + threadIdx.x) * 4;
    float4 va = *(const float4*)(a + idx);
    float4 vb = *(const float4*)(b + idx);
    ushort4 ra, rb;
    ra.x = f2bf_rne(va.x); ra.y = f2bf_rne(va.y); ra.z = f2bf_rne(va.z); ra.w = f2bf_rne(va.w);
    rb.x = f2bf_rne(vb.x); rb.y = f2bf_rne(vb.y); rb.z = f2bf_rne(vb.z); rb.w = f2bf_rne(vb.w);
    *(ushort4*)(oa + idx) = ra;
    *(ushort4*)(ob + idx) = rb;
}

// Fused C = img @ txt^T tile + softplus-reduction epilogue. Never materializes C.
// loss*N = sum_all [max(t,0)+exp(-|t|)] - sum_diag t,   t = scale*dot + bias
__global__ __launch_bounds__(256)
void siglip_gemm_loss_kernel(const unsigned short* __restrict__ A,   // img bf16 [N][D]
                             const unsigned short* __restrict__ B,   // txt bf16 [N][D]
                             const float* __restrict__ scale_p,
                             const float* __restrict__ bias_p,
                             float* __restrict__ out) {
    __shared__ unsigned short sA[BM * LDK];
    __shared__ unsigned short sB[BN * LDK];
    __shared__ float red[4];

    const int tid  = threadIdx.x;
    const int bRow = blockIdx.x, bCol = blockIdx.y;
    const size_t rowBase = (size_t)bRow * BM;
    const size_t colBase = (size_t)bCol * BN;

    const int wave = tid >> 6, lane = tid & 63;
    const int wr = wave >> 1, wc = wave & 1;       // 2x2 waves over 128x128
    const int m0 = wr * 64, n0 = wc * 64;          // wave's 64x64 subtile
    const int fm = lane & 15, quad = lane >> 4;    // fragment row / k-quad

    floatx4 acc[4][4];
    #pragma unroll
    for (int i = 0; i < 4; ++i)
        #pragma unroll
        for (int j = 0; j < 4; ++j)
            acc[i][j] = (floatx4){0.f, 0.f, 0.f, 0.f};

    // staging: thread t loads 16B (8 bf16); 8 threads/row, 32 rows/step, 4 steps
    const int srow = tid >> 3;
    const int scol = (tid & 7) * 8;

    for (int k0 = 0; k0 < kD; k0 += BK) {
        #pragma unroll
        for (int s = 0; s < 4; ++s) {
            int r = srow + s * 32;
            uint4 va = *(const uint4*)(A + (rowBase + r) * kD + k0 + scol);
            uint4 vb = *(const uint4*)(B + (colBase + r) * kD + k0 + scol);
            *(uint4*)(sA + r * LDK + scol) = va;
            *(uint4*)(sB + r * LDK + scol) = vb;
        }
        __syncthreads();
        #pragma unroll
        for (int kk = 0; kk < BK; kk += 32) {
            short8 af[4], bf[4];
            #pragma unroll
            for (int i = 0; i < 4; ++i) {
                af[i] = *(const short8*)(sA + (m0 + i*16 + fm) * LDK + kk + quad*8);
                bf[i] = *(const short8*)(sB + (n0 + i*16 + fm) * LDK + kk + quad*8);
            }
            #pragma unroll
            for (int i = 0; i < 4; ++i)
                #pragma unroll
                for (int j = 0; j < 4; ++j)
                    acc[i][j] = __builtin_amdgcn_mfma_f32_16x16x32_bf16(af[i], bf[j], acc[i][j], 0, 0, 0);
        }
        __syncthreads();
    }

    // Epilogue: label-free softplus term on every element
    const float sc = *scale_p;
    const float bs = *bias_p;
    float sum = 0.f;
    #pragma unroll
    for (int i = 0; i < 4; ++i)
        #pragma unroll
        for (int j = 0; j < 4; ++j)
            #pragma unroll
            for (int r = 0; r < 4; ++r) {
                float t = fmaf(acc[i][j][r], sc, bs);
                sum += fmaxf(t, 0.f) + __expf(-fabsf(t));
            }

    // Diagonal correction: term_diag = term_off - t. C/D layout: col=lane&15, row=quad*4+reg.
    // Diag element iff i==j (with bRow==bCol, wr==wc) and quad*4+r == fm  (symmetric in row/col).
    if (bRow == bCol && wr == wc && (fm >> 2) == quad) {
        const int r = fm & 3;
        #pragma unroll
        for (int i = 0; i < 4; ++i)
            sum -= fmaf(acc[i][i][r], sc, bs);
    }

    // block reduce -> one atomic per block
    #pragma unroll
    for (int off = 32; off > 0; off >>= 1)
        sum += __shfl_down(sum, off);
    if (lane == 0) red[wave] = sum;
    __syncthreads();
    if (tid == 0) {
        float s = (red[0] + red[1]) + (red[2] + red[3]);
        atomicAdd(out, s * (1.0f / (float)kN));
    }
}

extern "C" void kernel_launch(void* const* d_in, const int* in_sizes, int n_in,
                              void* d_out, int out_size, void* d_ws, size_t ws_size,
                              hipStream_t stream) {
    const float* img     = (const float*)d_in[0];
    const float* txt     = (const float*)d_in[1];
    const float* scale_p = (const float*)d_in[2];
    const float* bias_p  = (const float*)d_in[3];
    float* out = (float*)d_out;

    unsigned short* Abf = (unsigned short*)d_ws;                 // N*D bf16 = 8 MiB
    unsigned short* Bbf = Abf + (size_t)kN * kD;                 // N*D bf16 = 8 MiB

    hipMemsetAsync(out, 0, sizeof(float), stream);               // capture-safe
    cvt_bf16_kernel<<<dim3(kN * kD / 4 / 256), dim3(256), 0, stream>>>(img, txt, Abf, Bbf);
    dim3 grid(kN / BM, kN / BN);
    siglip_gemm_loss_kernel<<<grid, dim3(256), 0, stream>>>(Abf, Bbf, scale_p, bias_p, out);
}